// Round 8
// baseline (192.776 us; speedup 1.0000x reference)
//
#include <hip/hip_runtime.h>

typedef __attribute__((ext_vector_type(4))) float f32x4;
typedef __attribute__((ext_vector_type(8))) short short8;
typedef __attribute__((ext_vector_type(4))) unsigned int u32x4;
typedef unsigned short u16;
typedef unsigned int u32;
typedef unsigned long long u64;

__device__ __forceinline__ u16 f2bf(float f) {
  u32 u = __builtin_bit_cast(u32, f);
  u += 0x7fffu + ((u >> 16) & 1u);
  return (u16)(u >> 16);
}
__device__ __forceinline__ u16 f2bf_t(float f) {
  return (u16)(__builtin_bit_cast(u32, f) >> 16);
}

// ===========================================================================
// Fragment-major layouts (16x16x32 bf16 MFMA, lane = quad*16 + l15):
//   A-frag block (1KB): elem[lane][j] = A[rt*16 + l15][kt*64 + kk*32 + quad*8 + j]
//   B-frag block (1KB): elem[lane][j] = W[kt*64 + kk*32 + quad*8 + j][nt*16 + l15]
//   flat offset: ((rt_or_nt * KT + kt) * 2 + kk) * 512 + lane * 8
// Every hot GEMM/attn load is one fully-coalesced 1KB b128 instruction.
// ===========================================================================

// ---------------------------------------------------------------------------
// prep: emits xfrag/ctxfrag (A-frag-major, cast fp32->bf16) and
// wqfrag/wkvfrag/wofrag (B-frag-major, transpose+cast). One dispatch.
//   [0,1024):    x    (64-row x 64-k tiles)
//   [1024,1792): ctx
//   [1792,2048): Wq    [2048,2432): Wkv    [2432,2688): Wo
// ---------------------------------------------------------------------------
__device__ __forceinline__ void cast_stage(const float* __restrict__ src,
                                           int stride, int m0, int k0, int tid,
                                           u16* T) {
  int row = tid >> 2, cg = tid & 3;
  const float* p = src + (long)(m0 + row) * stride + k0 + cg * 16;
  u16 tmp[16];
#pragma unroll
  for (int q = 0; q < 4; q++) {
    f32x4 f = ((const f32x4*)p)[q];
#pragma unroll
    for (int j = 0; j < 4; j++) tmp[q * 4 + j] = f2bf(f[j]);
  }
  *(u32x4*)&T[row * 72 + cg * 16] = ((u32x4*)tmp)[0];
  *(u32x4*)&T[row * 72 + cg * 16 + 8] = ((u32x4*)tmp)[1];
}

__device__ __forceinline__ void trans_stage(const float* __restrict__ W, int N,
                                            int k0, int n0, int tid, u16* T) {
#pragma unroll
  for (int i = 0; i < 4; i++) {
    int c = tid + 256 * i;
    int row = c >> 4;  // k_local
    int ch = c & 15;   // n chunk of 4
    f32x4 f = *(const f32x4*)(W + (long)(k0 + row) * N + n0 + ch * 4);
#pragma unroll
    for (int j = 0; j < 4; j++) T[(ch * 4 + j) * 72 + row] = f2bf(f[j]);
  }
}

// T holds tile[r][c] (r = m or n, c = k), stride 72. Emit 8 frag blocks.
__device__ __forceinline__ void frag_emit(const u16* T, u16* __restrict__ out,
                                          int r0t, int kt, int KT, int tid) {
#pragma unroll
  for (int p = 0; p < 2; p++) {
    int s = tid + 256 * p;  // 0..511: sub(2b..) kk lane
    int sub = s >> 7, kk = (s >> 6) & 1, lane = s & 63;
    const u16* src = &T[(sub * 16 + (s & 15)) * 72 + kk * 32 + ((s >> 4) & 3) * 8];
    u16* dst = out + (((long)(r0t + sub) * KT + kt) * 2 + kk) * 512 + lane * 8;
    *(u32x4*)dst = *(const u32x4*)src;
  }
}

__global__ __launch_bounds__(256) void prep(
    const float* __restrict__ x, const float* __restrict__ ctx,
    const float* __restrict__ Wq, const float* __restrict__ Wkv,
    const float* __restrict__ Wo, u16* __restrict__ xfrag,
    u16* __restrict__ ctxfrag, u16* __restrict__ wqfrag,
    u16* __restrict__ wkvfrag, u16* __restrict__ wofrag) {
  __shared__ __align__(16) u16 T[64 * 72];
  const int bid = blockIdx.x, tid = threadIdx.x;
  const float* src;
  u16* out;
  int m0, k0, KT, stride;
  bool isA;
  if (bid < 1024) {
    isA = true; src = x; out = xfrag; stride = 1024; KT = 16;
    m0 = (bid >> 4) * 64; k0 = (bid & 15) * 64;
  } else if (bid < 1792) {
    int i = bid - 1024;
    isA = true; src = ctx; out = ctxfrag; stride = 768; KT = 12;
    m0 = (i / 12) * 64; k0 = (i % 12) * 64;
  } else if (bid < 2048) {
    int i = bid - 1792;
    isA = false; src = Wq; out = wqfrag; stride = 1024; KT = 16;
    k0 = (i >> 4) * 64; m0 = (i & 15) * 64;  // m0 := n0
  } else if (bid < 2432) {
    int i = bid - 2048;
    isA = false; src = Wkv; out = wkvfrag; stride = 2048; KT = 12;
    k0 = (i >> 5) * 64; m0 = (i & 31) * 64;
  } else {
    int i = bid - 2432;
    isA = false; src = Wo; out = wofrag; stride = 1024; KT = 16;
    k0 = (i >> 4) * 64; m0 = (i & 15) * 64;
  }
  if (isA)
    cast_stage(src, stride, m0, k0, tid, T);
  else
    trans_stage(src, stride, k0, m0, tid, T);
  __syncthreads();
  frag_emit(T, out, m0 >> 4, k0 >> 6, KT, tid);
}

// ---------------------------------------------------------------------------
// Barrier-free stream GEMM core: 128x128 block, 4 waves 2x2 (64x64 each),
// A/B both fragment-major in global. Per K-step: 16 coalesced b128 loads +
// 32 MFMA; register ping-pong 1-step prefetch; NO LDS, NO barriers.
// ---------------------------------------------------------------------------
__device__ __forceinline__ void mfma_block(f32x4 (&acc)[4][4],
                                           short8 (&af)[2][4],
                                           short8 (&bf)[2][4]) {
#pragma unroll
  for (int kk = 0; kk < 2; kk++)
#pragma unroll
    for (int i = 0; i < 4; i++)
#pragma unroll
      for (int j = 0; j < 4; j++)
        acc[i][j] = __builtin_amdgcn_mfma_f32_16x16x32_bf16(
            af[kk][i], bf[kk][j], acc[i][j], 0, 0, 0);
}

template <int KT>
__device__ __forceinline__ void gemm_stream(const u16* __restrict__ AF,
                                            const u16* __restrict__ BF,
                                            long rt0, long nt0, int lane,
                                            int wv, f32x4 (&acc)[4][4]) {
  const u16* ab[4];
  const u16* bb[4];
#pragma unroll
  for (int n = 0; n < 4; n++) {
    ab[n] = AF + ((rt0 + (wv >> 1) * 4 + n) * KT) * 1024 + lane * 8;
    bb[n] = BF + ((nt0 + (wv & 1) * 4 + n) * KT) * 1024 + lane * 8;
  }
  short8 a0[2][4], b0[2][4], a1[2][4], b1[2][4];
  auto ld = [&](short8(&A)[2][4], short8(&B)[2][4], int kt) {
#pragma unroll
    for (int kk = 0; kk < 2; kk++)
#pragma unroll
      for (int n = 0; n < 4; n++) {
        A[kk][n] = *(const short8*)(ab[n] + kt * 1024 + kk * 512);
        B[kk][n] = *(const short8*)(bb[n] + kt * 1024 + kk * 512);
      }
  };
  ld(a0, b0, 0);
  for (int kt = 0; kt < KT; kt += 2) {
    if (kt + 1 < KT) ld(a1, b1, kt + 1);
    mfma_block(acc, a0, b0);
    if (kt + 2 < KT) ld(a0, b0, kt + 2);
    mfma_block(acc, a1, b1);
  }
}

// ---------------------------------------------------------------------------
// Fused Q-proj + KV-proj (stream GEMMs). Grid 768:
//   bid <  256: Q = x @ Wq -> Qb row-major bf16 (*qscale)
//   bid >= 256: KV = ctx @ Wkv -> Kfrag / Vfrag (r7 epilogues, verified)
// ---------------------------------------------------------------------------
__global__ __launch_bounds__(256, 2) void fused_qkv(
    const u16* __restrict__ xfrag, const u16* __restrict__ ctxfrag,
    const u16* __restrict__ wqfrag, const u16* __restrict__ wkvfrag,
    u16* __restrict__ Qb, u16* __restrict__ Kfrag, u16* __restrict__ Vfrag,
    float qscale) {
  __shared__ __align__(16) u16 As[8192];
  const int tid = threadIdx.x;
  const int lane = tid & 63, wv = tid >> 6;
  const int l15 = lane & 15, quad = lane >> 4;
  const int wr = (wv >> 1) * 64, wc = (wv & 1) * 64;

  f32x4 acc[4][4];
#pragma unroll
  for (int i = 0; i < 4; i++)
#pragma unroll
    for (int j = 0; j < 4; j++) acc[i][j] = (f32x4){0.f, 0.f, 0.f, 0.f};

  int bid = blockIdx.x;
  if (bid < 256) {
    long rt0 = (long)(bid >> 3) * 8, nt0 = (long)(bid & 7) * 8;
    gemm_stream<16>(xfrag, wqfrag, rt0, nt0, lane, wv, acc);
    long brow = rt0 * 16, bcol = nt0 * 16;
#pragma unroll
    for (int i = 0; i < 4; i++)
#pragma unroll
      for (int j = 0; j < 4; j++)
#pragma unroll
        for (int r = 0; r < 4; r++) {
          long row = brow + wr + i * 16 + quad * 4 + r;
          long col = bcol + wc + j * 16 + l15;
          Qb[row * 1024 + col] = f2bf(acc[i][j][r] * qscale);
        }
    return;
  }

  bid -= 256;
  long rt0 = (long)(bid >> 4) * 8, nt0 = (long)(bid & 15) * 8;
  gemm_stream<12>(ctxfrag, wkvfrag, rt0, nt0, lane, wv, acc);
  long brow = rt0 * 16, bcol = nt0 * 16;

  const bool is_k = (bcol < 1024);
  __syncthreads();
#pragma unroll
  for (int round = 0; round < 2; round++) {
    if ((wv >> 1) == round) {
      if (is_k) {
#pragma unroll
        for (int i = 0; i < 4; i++)
#pragma unroll
          for (int j = 0; j < 4; j++) {
            int d = j * 16 + l15;
            int off = (wv & 1) * 4096 + ((d >> 5) * 4 + i) * 512 +
                      (((d >> 3) & 3) * 16 + quad * 4) * 8 + (d & 7);
#pragma unroll
            for (int r = 0; r < 4; r++) As[off + r * 8] = f2bf(acc[i][j][r]);
          }
      } else {
#pragma unroll
        for (int i = 0; i < 4; i++)
#pragma unroll
          for (int j = 0; j < 4; j++) {
            int off = (wv & 1) * 4096 + ((i >> 1) * 4 + j) * 512 +
                      (quad * 16 + l15) * 8 + (i & 1) * 4;
            u16 t4[4];
#pragma unroll
            for (int r = 0; r < 4; r++) t4[r] = f2bf(acc[i][j][r]);
            *(u64*)&As[off] = *(const u64*)t4;
          }
      }
    }
    __syncthreads();
    long mg = brow + round * 64;
    int b_ = (int)(mg >> 11), mt = (int)((mg >> 6) & 31);
#pragma unroll
    for (int h2 = 0; h2 < 2; h2++) {
      int h = (int)((is_k ? bcol : bcol - 1024) >> 6) + h2;
      u16* dst = (is_k ? Kfrag : Vfrag) + ((long)(b_ * 16 + h) * 32 + mt) * 4096;
#pragma unroll
      for (int p = 0; p < 2; p++) {
        int c = p * 256 + tid;
        *(u32x4*)(dst + c * 8) = *(u32x4*)&As[h2 * 4096 + c * 8];
      }
    }
    __syncthreads();
  }
}

// ---------------------------------------------------------------------------
// O-projection: barrier-free stream (A = AOF frag-major from attn, B = wofrag),
// fp32 row-major out. Grid 256.
// ---------------------------------------------------------------------------
__global__ __launch_bounds__(256, 2) void gemm_o(
    const u16* __restrict__ AOF, const u16* __restrict__ wofrag,
    float* __restrict__ C) {
  const int tid = threadIdx.x;
  const int lane = tid & 63, wv = tid >> 6;
  const int l15 = lane & 15, quad = lane >> 4;
  const int wr = (wv >> 1) * 64, wc = (wv & 1) * 64;
  long rt0 = (long)(blockIdx.x >> 3) * 8, nt0 = (long)(blockIdx.x & 7) * 8;

  f32x4 acc[4][4];
#pragma unroll
  for (int i = 0; i < 4; i++)
#pragma unroll
    for (int j = 0; j < 4; j++) acc[i][j] = (f32x4){0.f, 0.f, 0.f, 0.f};

  gemm_stream<16>(AOF, wofrag, rt0, nt0, lane, wv, acc);

  long brow = rt0 * 16, bcol = nt0 * 16;
#pragma unroll
  for (int i = 0; i < 4; i++)
#pragma unroll
    for (int j = 0; j < 4; j++)
#pragma unroll
      for (int r = 0; r < 4; r++) {
        long row = brow + wr + i * 16 + quad * 4 + r;
        long col = bcol + wc + j * 16 + l15;
        C[row * 1024 + col] = acc[i][j][r];
      }
}

// ---------------------------------------------------------------------------
// Flash attention v8: r7 core (barrier-free K/V fragment stream, S^T trick,
// fixed-shift softmax, ones-MFMA row-sum) + epilogue now writes AO in
// A-fragment-major (LDS transpose) for gemm_o's stream. 1-D grid 512 with
// XCD swizzle (bh = bid & 31 -> same-bh blocks share an XCD's L2).
// ---------------------------------------------------------------------------
__global__ __launch_bounds__(256, 2) void attn_kernel(
    const u16* __restrict__ Q, const u16* __restrict__ Kfrag,
    const u16* __restrict__ Vfrag, u16* __restrict__ AOF) {
  __shared__ __align__(16) u16 T2[128 * 72];
  const int tid = threadIdx.x;
  const int lane = tid & 63, wave = tid >> 6;
  const int l15 = lane & 15, quad = lane >> 4;
  const int bh = blockIdx.x & 31;
  const int b = bh >> 4, h = bh & 15;
  const long qrow0 = (long)b * 2048 + (blockIdx.x >> 5) * 128;

  short8 qf[2][2];
#pragma unroll
  for (int qt = 0; qt < 2; qt++)
#pragma unroll
    for (int kk = 0; kk < 2; kk++)
      qf[qt][kk] = *(const short8*)&Q[(qrow0 + wave * 32 + qt * 16 + l15) * 1024 +
                                      h * 64 + kk * 32 + quad * 8];

  f32x4 O[2][5];
#pragma unroll
  for (int qt = 0; qt < 2; qt++)
#pragma unroll
    for (int dt = 0; dt < 5; dt++) O[qt][dt] = (f32x4){0.f, 0.f, 0.f, 0.f};

  u32x4 ones_u = {0x3F803F80u, 0x3F803F80u, 0x3F803F80u, 0x3F803F80u};
  short8 ones = __builtin_bit_cast(short8, ones_u);

  const u16* kbase = Kfrag + (long)bh * 32 * 4096 + lane * 8;
  const u16* vbase = Vfrag + (long)bh * 32 * 4096 + lane * 8;

  auto load_k = [&](short8(&kf)[2][4], int tile) {
    const u16* kt = kbase + (long)tile * 4096;
#pragma unroll
    for (int kk = 0; kk < 2; kk++)
#pragma unroll
      for (int t = 0; t < 4; t++)
        kf[kk][t] = *(const short8*)(kt + (kk * 4 + t) * 512);
  };

  auto step = [&](short8(&kc)[2][4], short8(&kn)[2][4], int tile) {
    short8 vf[2][4];
    const u16* vt = vbase + (long)tile * 4096;
#pragma unroll
    for (int kk = 0; kk < 2; kk++)
#pragma unroll
      for (int dt = 0; dt < 4; dt++)
        vf[kk][dt] = *(const short8*)(vt + (kk * 4 + dt) * 512);
    if (tile + 1 < 32) load_k(kn, tile + 1);

    f32x4 s[4][2];
#pragma unroll
    for (int m4 = 0; m4 < 4; m4++)
#pragma unroll
      for (int qt = 0; qt < 2; qt++) s[m4][qt] = (f32x4){0.f, 0.f, 0.f, 0.f};
#pragma unroll
    for (int kk = 0; kk < 2; kk++)
#pragma unroll
      for (int m4 = 0; m4 < 4; m4++)
#pragma unroll
        for (int qt = 0; qt < 2; qt++)
          s[m4][qt] = __builtin_amdgcn_mfma_f32_16x16x32_bf16(
              kc[kk][m4], qf[qt][kk], s[m4][qt], 0, 0, 0);

#pragma unroll
    for (int kk = 0; kk < 2; kk++) {
#pragma unroll
      for (int qt = 0; qt < 2; qt++) {
        u32 w[4];
#pragma unroll
        for (int half = 0; half < 2; half++) {
          f32x4 sv = s[2 * kk + half][qt];
          u32 lo = (u32)f2bf_t(__builtin_amdgcn_exp2f(sv[0] - 24.f)) |
                   ((u32)f2bf_t(__builtin_amdgcn_exp2f(sv[1] - 24.f)) << 16);
          u32 hi = (u32)f2bf_t(__builtin_amdgcn_exp2f(sv[2] - 24.f)) |
                   ((u32)f2bf_t(__builtin_amdgcn_exp2f(sv[3] - 24.f)) << 16);
          w[half * 2] = lo;
          w[half * 2 + 1] = hi;
        }
        short8 pa = __builtin_bit_cast(short8, *(u32x4*)w);
#pragma unroll
        for (int dt = 0; dt < 4; dt++)
          O[qt][dt] = __builtin_amdgcn_mfma_f32_16x16x32_bf16(
              pa, vf[kk][dt], O[qt][dt], 0, 0, 0);
        O[qt][4] = __builtin_amdgcn_mfma_f32_16x16x32_bf16(
            pa, ones, O[qt][4], 0, 0, 0);
      }
    }
  };

  short8 ka[2][4], kb2[2][4];
  load_k(ka, 0);
  for (int tile = 0; tile < 32; tile += 2) {
    step(ka, kb2, tile);
    step(kb2, ka, tile + 1);
  }

  // epilogue: normalize, LDS transpose (C-layout -> row x d), emit A-frags
#pragma unroll
  for (int qt = 0; qt < 2; qt++) {
    float inv[4];
#pragma unroll
    for (int r = 0; r < 4; r++) inv[r] = 1.f / O[qt][4][r];
#pragma unroll
    for (int dt = 0; dt < 4; dt++)
#pragma unroll
      for (int r = 0; r < 4; r++)
        T2[(wave * 32 + qt * 16 + quad * 4 + r) * 72 + dt * 16 + l15] =
            f2bf(O[qt][dt][r] * inv[r]);
  }
  __syncthreads();
  const long rtb = qrow0 >> 4;
#pragma unroll
  for (int p = 0; p < 4; p++) {
    int s = tid + 256 * p;  // 1024 slots: rt_l(3b) kk(1b) lane(6b)
    int rt_l = s >> 7, kk = (s >> 6) & 1, ln = s & 63;
    const u16* src = &T2[(rt_l * 16 + (s & 15)) * 72 + kk * 32 + ((s >> 4) & 3) * 8];
    u16* dst = AOF + (((rtb + rt_l) * 16 + h) * 2 + kk) * 512 + ln * 8;
    *(u32x4*)dst = *(const u32x4*)src;
  }
}

// ---------------------------------------------------------------------------
extern "C" void kernel_launch(void* const* d_in, const int* in_sizes, int n_in,
                              void* d_out, int out_size, void* d_ws,
                              size_t ws_size, hipStream_t stream) {
  const float* x = (const float*)d_in[0];     // [2,2048,1024]
  const float* ctx = (const float*)d_in[1];   // [2,2048,768]
  const float* Wq = (const float*)d_in[2];    // [1024,1024]
  const float* Wkv = (const float*)d_in[3];   // [768,2048]
  const float* Wo = (const float*)d_in[4];    // [1024,1024]
  float* out = (float*)d_out;                 // [2,2048,1024] fp32

  u16* ws = (u16*)d_ws;
  u16* wqfrag = ws;                    // 1M elems  (B-frag, KT=16)
  u16* wkvfrag = wqfrag + 1048576;     // 1.5M      (B-frag, KT=12)
  u16* wofrag = wkvfrag + 1572864;     // 1M        (B-frag, KT=16)
  u16* Qb = wofrag + 1048576;          // 4M  [4096][1024] row-major (q-scaled)
  u16* Kfrag = Qb + 4194304;           // 4M  [32 bh][32 mt][4096]
  u16* Vfrag = Kfrag + 4194304;        // 4M  [32 bh][32 mt][4096]
  u16* xfrag = Vfrag + 4194304;        // 4M  (A-frag, KT=16; aliased: AOF)
  u16* ctxfrag = xfrag + 4194304;      // 3M  (A-frag, KT=12)
  u16* AOF = xfrag;  // xfrag dead after fused_qkv

  const float qscale = 0.125f * 1.4426950408889634f;  // Dh^-0.5 * log2(e)

  prep<<<dim3(2688), 256, 0, stream>>>(x, ctx, Wq, Wkv, Wo, xfrag, ctxfrag,
                                       wqfrag, wkvfrag, wofrag);

  fused_qkv<<<dim3(768), 256, 0, stream>>>(xfrag, ctxfrag, wqfrag, wkvfrag,
                                           Qb, Kfrag, Vfrag, qscale);

  attn_kernel<<<dim3(512), 256, 0, stream>>>(Qb, Kfrag, Vfrag, AOF);

  gemm_o<<<dim3(256), 256, 0, stream>>>(AOF, wofrag, out);
}